// Round 7
// baseline (1327.736 us; speedup 1.0000x reference)
//
#include <hip/hip_runtime.h>
#include <hip/hip_bf16.h>

#define WSZ 8
#define NHE 4
#define CH 64
#define WPB 4   // windows per block

typedef unsigned short u16;
typedef unsigned int u32;
typedef __attribute__((ext_vector_type(8))) short short8;
typedef __attribute__((ext_vector_type(4))) short short4v;
typedef __attribute__((ext_vector_type(4))) float float4v;

// Native bf16 conversion (RNE). Compiler packs pairs into v_cvt_pk_bf16_f32.
__device__ __forceinline__ u16 f2bf(float f) {
    __hip_bfloat16 h = __float2bfloat16(f);
    return __builtin_bit_cast(u16, h);
}
// XOR swizzle for [row][64] bf16 arrays: keeps 8-elem (16B) chunks intact,
// spreads the 8 chunk slots across banks by row.
__device__ __forceinline__ int SW(int row, int col) {
    return row * 64 + (col ^ ((row & 7) << 3));
}

#define MFMA(a, b, c) __builtin_amdgcn_mfma_f32_16x16x32_bf16(a, b, c, 0, 0, 0)
#define QKSC 0.36067376022224085f   /* 0.25 * log2(e) */

// ---- pre-kernel: bf16 weights in per-lane fragment layout + rpb expanded to
// a coalesced bias table matching the TRANSPOSED-S lane mapping (verified R3/R5),
// PRE-SCALED by log2(e) for the exp2-domain softmax:
//   idx = ((h*4+mt)*64 + lane)*16 + nt*4 + r,
//   query tokm = mt*16 + (lane&15), key tokn = nt*16 + (lane>>4)*4 + r
__global__ void prep(const float* __restrict__ qkvw, const float* __restrict__ projw,
                     const float* __restrict__ rpb,
                     u16* __restrict__ wq, u16* __restrict__ wp, float* __restrict__ bl)
{
    int t = blockIdx.x * 256 + threadIdx.x;   // 64 blocks x 256 = 16384
    if (t < 12288) {  // qkv weights: layout [nt][kt][q][nl][8]
        int j = t & 7, nl = (t >> 3) & 15, q = (t >> 7) & 3, kt = (t >> 9) & 1, nt = t >> 10;
        wq[t] = f2bf(qkvw[(nt * 16 + nl) * CH + kt * 32 + q * 8 + j]);
    }
    if (t < 4096) {   // proj weights: layout [wv][kt][q][nl][8]
        int j = t & 7, nl = (t >> 3) & 15, q = (t >> 7) & 3, kt = (t >> 9) & 1, wv = t >> 10;
        wp[t] = f2bf(projw[(wv * 16 + nl) * CH + kt * 32 + q * 8 + j]);
    }
    if (t < 16384) {  // bias table for transposed-S softmax (log2-domain)
        int r = t & 3, nt = (t >> 2) & 3, lane = (t >> 4) & 63, mt = (t >> 10) & 3, h = t >> 12;
        int nl = lane & 15, q = lane >> 4;
        int tokm = mt * 16 + nl, tokn = nt * 16 + q * 4 + r;
        int im = tokm >> 3, jm = tokm & 7, in_ = tokn >> 3, jn = tokn & 7;
        bl[t] = rpb[((im - in_ + 7) * 15 + (jm - jn + 7)) * NHE + h] * 1.44269504088896341f;
    }
}

// 4 waves/block; each block processes WPB=4 CONSECUTIVE windows (same L2 lines).
// LDS = 32768 B -> 5 blocks/CU. Aliasing identical to R5 (all barrier-separated):
//   [0..16384)    XS fp32 [64ch][64tok] (ph0-1) -> QO bf16 + KS bf16 (ph2+)
//   [16384..24576) XN bf16 swz (ph1-2a) -> per-wave P (ph3)
//   [24576..32768) PS/PS2 LN scratch (ph1) -> VS bf16 [64ch][64tok] (ph2+)
// Loop-end barrier protects next ph0's XS write vs ph4's QO reads.
// x for window w+1 is PREFETCHED into registers during window w's ph2a.
__global__ __launch_bounds__(256, 5) void win_attn(
    const float* __restrict__ x, const float* __restrict__ nw, const float* __restrict__ nb,
    const u16* __restrict__ wq, const u16* __restrict__ wp,
    const float* __restrict__ ascale, const float* __restrict__ biasl,
    float* __restrict__ out, int B, int H, int W)
{
    const int HWsz = H * W;
    const int nww = W / WSZ, nwh = H / WSZ;
    // XCD-chunked swizzle over BLOCKS (gridDim %8==0): XCD k gets a contiguous
    // window range; within a block, WPB consecutive windows share x/out lines.
    const int NBLK = (int)gridDim.x;
    const int swz = (blockIdx.x & 7) * (NBLK >> 3) + ((int)blockIdx.x >> 3);

    const int tid  = threadIdx.x;
    const int lane = tid & 63;
    const int wv   = tid >> 6;
    const int q    = lane >> 4;   // quad
    const int nl   = lane & 15;

    __shared__ alignas(16) char smem[32768];
    float* XS  = (float*)(smem);
    u16*   QO  = (u16*)(smem);
    u16*   KS  = (u16*)(smem + 8192);
    u16*   XN  = (u16*)(smem + 16384);
    u16*   VS  = (u16*)(smem + 24576);
    float* PS  = (float*)(smem + 24576);
    float* PS2 = PS + 256;

    // ---- block-invariant: weight fragments + scale (loaded ONCE per block) ----
    short8 bfrs[3][2];
    #pragma unroll
    for (int nt3 = 0; nt3 < 3; nt3++) {
        int nt = wv * 3 + nt3;
        #pragma unroll
        for (int kt = 0; kt < 2; kt++)
            bfrs[nt3][kt] = *(const short8*)&wq[((((nt * 2 + kt) * 4 + q) * 16) + nl) * 8];
    }
    short8 wfr[2];
    #pragma unroll
    for (int kt = 0; kt < 2; kt++)
        wfr[kt] = *(const short8*)&wp[((((wv * 2 + kt) * 4 + q) * 16) + nl) * 8];
    const float asc = ascale[0];

    // per-thread fixed ph0/prefetch indices: thread covers channels pc0+it*16
    const int pc0 = tid >> 4;
    const int pr  = tid & 15;
    const int pi  = pr >> 1, pj4 = (pr & 1) * 4;

    int cw = swz * WPB;          // current window
    int rowbase, b;
    {
        int ww = cw % nww, t1 = cw / nww, wh = t1 % nwh; b = t1 / nwh;
        rowbase = (wh * WSZ) * W + ww * WSZ;
    }
    const float* xw = x + (size_t)b * CH * HWsz + rowbase;

    // prefetch window 0's x into registers
    float4v pre[4];
    #pragma unroll
    for (int it = 0; it < 4; it++)
        pre[it] = *(const float4v*)(xw + (size_t)(pc0 + it * 16) * HWsz + pi * W + pj4);

    for (int wi = 0; wi < WPB; wi++) {
        // ---- phase 0: registers -> XS [ch][tok] ----
        #pragma unroll
        for (int it = 0; it < 4; it++)
            *(float4v*)&XS[(pc0 + it * 16) * 64 + pi * 8 + pj4] = pre[it];
        __syncthreads();

        // ---- phase 1a: LayerNorm partials (split across waves) ----
        {
            float s = 0.f, s2 = 0.f;
            #pragma unroll
            for (int ci = 0; ci < 16; ci++) {
                float v = XS[(wv * 16 + ci) * 64 + lane];
                s += v; s2 += v * v;
            }
            PS[wv * 64 + lane] = s;
            PS2[wv * 64 + lane] = s2;
        }
        __syncthreads();
        // ---- phase 1b: per-lane finalize; write XN ----
        {
            float s  = PS[lane]  + PS[64 + lane]  + PS[128 + lane]  + PS[192 + lane];
            float s2 = PS2[lane] + PS2[64 + lane] + PS2[128 + lane] + PS2[192 + lane];
            float mu  = s * (1.f / 64.f);
            float var = s2 * (1.f / 64.f) - mu * mu;
            float rs  = rsqrtf(var + 1e-5f);
            #pragma unroll
            for (int ci = 0; ci < 16; ci++) {
                int c = wv * 16 + ci;                       // wave-uniform -> s_load nw/nb
                float v = (XS[c * 64 + lane] - mu) * rs * nw[c] + nb[c];
                XN[SW(lane, c)] = f2bf(v);
            }
        }
        __syncthreads();

        // ---- phase 2a: A-fragments from XN; issue NEXT window's x prefetch ----
        short8 afr[4][2];
        #pragma unroll
        for (int mt = 0; mt < 4; mt++)
            #pragma unroll
            for (int kt = 0; kt < 2; kt++) {
                int m = mt * 16 + nl;
                int phys = (kt * 4 + q) ^ (m & 7);
                afr[mt][kt] = *(short8*)&XN[m * 64 + phys * 8];
            }
        int nrowbase = rowbase, nb2 = b;
        const float* xwn = xw;
        if (wi + 1 < WPB) {
            int nwin2 = cw + 1;
            int ww = nwin2 % nww, t1 = nwin2 / nww, wh = t1 % nwh; nb2 = t1 / nwh;
            nrowbase = (wh * WSZ) * W + ww * WSZ;
            xwn = x + (size_t)nb2 * CH * HWsz + nrowbase;
            #pragma unroll
            for (int it = 0; it < 4; it++)
                pre[it] = *(const float4v*)(xwn + (size_t)(pc0 + it * 16) * HWsz + pi * W + pj4);
        }

        // ---- phase 2b: QKV GEMM (M=64, N=192, K=64), wave w owns n-tiles 3w..3w+2 ----
        #pragma unroll
        for (int nt3 = 0; nt3 < 3; nt3++) {
            int nt = wv * 3 + nt3;
            int which = nt >> 2;                 // 0:Q 1:K 2:V (wave-uniform)
            int chb = (nt & 3) * 16 + nl;        // output channel within q/k/v
            #pragma unroll
            for (int mt = 0; mt < 4; mt++) {
                float4v acc = {0.f, 0.f, 0.f, 0.f};
                acc = MFMA(afr[mt][0], bfrs[nt3][0], acc);
                acc = MFMA(afr[mt][1], bfrs[nt3][1], acc);
                int tok0 = mt * 16 + q * 4;
                if (which == 0) {
                    #pragma unroll
                    for (int r = 0; r < 4; r++) QO[SW(tok0 + r, chb)] = f2bf(acc[r]);
                } else if (which == 1) {
                    #pragma unroll
                    for (int r = 0; r < 4; r++) KS[SW(tok0 + r, chb)] = f2bf(acc[r]);
                } else {
                    short4v pk;
                    pk[0] = (short)f2bf(acc[0]); pk[1] = (short)f2bf(acc[1]);
                    pk[2] = (short)f2bf(acc[2]); pk[3] = (short)f2bf(acc[3]);
                    int pt = tok0 ^ ((chb & 7) << 3);    // V is [ch][tok]
                    *(short4v*)&VS[chb * 64 + pt] = pk;
                }
            }
        }
        __syncthreads();

        // ---- phase 3: attention, wave = head h (S^T softmax, verified R3/R5) ----
        {
            const int h = wv;
            u16* Pw = XN + wv * 1024;   // per-wave P (XN dead)
            const short8 zero8 = {0, 0, 0, 0, 0, 0, 0, 0};
            short8 kfr[4], vfr[2];
            #pragma unroll
            for (int nt = 0; nt < 4; nt++) {
                if (q < 2) {
                    int n = nt * 16 + nl;
                    int phys = (h * 2 + q) ^ (n & 7);
                    kfr[nt] = *(short8*)&KS[n * 64 + phys * 8];
                } else kfr[nt] = zero8;
            }
            #pragma unroll
            for (int kt = 0; kt < 2; kt++) {
                int c = h * 16 + nl;
                int phys = (kt * 4 + q) ^ (c & 7);
                vfr[kt] = *(short8*)&VS[c * 64 + phys * 8];
            }
            #pragma unroll
            for (int mt = 0; mt < 4; mt++) {
                short8 qf;
                if (q < 2) {
                    int m = mt * 16 + nl;
                    int phys = (h * 2 + q) ^ (m & 7);
                    qf = *(short8*)&QO[m * 64 + phys * 8];
                } else qf = zero8;
                const float4v* bp = (const float4v*)(biasl + ((((h * 4 + mt) * 64) + lane) << 4));
                float4v sacc[4];
                #pragma unroll
                for (int nt = 0; nt < 4; nt++) {
                    float4v z = {0.f, 0.f, 0.f, 0.f};
                    sacc[nt] = MFMA(kfr[nt], qf, z);   // transposed S
                }
                float p[16], mx = -1e30f;
                #pragma unroll
                for (int nt = 0; nt < 4; nt++) {
                    float4v blv = bp[nt];
                    #pragma unroll
                    for (int r = 0; r < 4; r++) {
                        float s = fmaf(sacc[nt][r], QKSC, blv[r]);   // log2-domain
                        p[nt * 4 + r] = s;
                        mx = fmaxf(mx, s);
                    }
                }
                mx = fmaxf(mx, __shfl_xor(mx, 16, 64));
                mx = fmaxf(mx, __shfl_xor(mx, 32, 64));
                float sum = 0.f;
                #pragma unroll
                for (int i = 0; i < 16; i++) {
                    float e = __builtin_amdgcn_exp2f(p[i] - mx);
                    p[i] = e;
                    sum += e;
                }
                sum += __shfl_xor(sum, 16, 64);
                sum += __shfl_xor(sum, 32, 64);
                float inv = __builtin_amdgcn_rcpf(sum);
                #pragma unroll
                for (int nt = 0; nt < 4; nt++)
                    #pragma unroll
                    for (int r = 0; r < 4; r++)
                        Pw[SW(nl, nt * 16 + q * 4 + r)] = f2bf(p[nt * 4 + r] * inv);
                // PV: O[mt] = P[16x64] @ V[64x16]  (per-wave LDS, in-order DS ops)
                float4v oacc = {0.f, 0.f, 0.f, 0.f};
                #pragma unroll
                for (int kt = 0; kt < 2; kt++) {
                    int phys = (kt * 4 + q) ^ (nl & 7);
                    short8 pf = *(short8*)&Pw[nl * 64 + phys * 8];
                    oacc = MFMA(pf, vfr[kt], oacc);
                }
                #pragma unroll
                for (int r = 0; r < 4; r++)
                    QO[SW(mt * 16 + q * 4 + r, h * 16 + nl)] = f2bf(oacc[r]);
            }
        }
        __syncthreads();

        // ---- phase 4: proj + residual; wave w owns out-channel tile w ----
        {
            const int ch = wv * 16 + nl;
            const float* xrp = xw + (size_t)ch * HWsz;   // residual (L2-hot)
            float4v xr[4];
            #pragma unroll
            for (int mt = 0; mt < 4; mt++) {
                int tok0 = mt * 16 + q * 4;
                xr[mt] = *(const float4v*)(xrp + (tok0 >> 3) * W + (tok0 & 7));
            }
            float* outp = out + ((size_t)b * CH + ch) * HWsz + rowbase;
            #pragma unroll
            for (int mt = 0; mt < 4; mt++) {
                float4v yacc = {0.f, 0.f, 0.f, 0.f};
                #pragma unroll
                for (int kt = 0; kt < 2; kt++) {
                    int m = mt * 16 + nl;
                    int phys = (kt * 4 + q) ^ (m & 7);
                    short8 of = *(short8*)&QO[m * 64 + phys * 8];
                    yacc = MFMA(of, wfr[kt], yacc);
                }
                int tok0 = mt * 16 + q * 4;
                int i = tok0 >> 3, j = tok0 & 7;
                float4v y;
                y[0] = xr[mt][0] + asc * yacc[0];
                y[1] = xr[mt][1] + asc * yacc[1];
                y[2] = xr[mt][2] + asc * yacc[2];
                y[3] = xr[mt][3] + asc * yacc[3];
                *(float4v*)(outp + i * W + j) = y;
            }
        }
        __syncthreads();   // protect next ph0's XS write vs this ph4's QO reads

        cw++;
        rowbase = nrowbase; b = nb2; xw = xwn;
    }
}

extern "C" void kernel_launch(void* const* d_in, const int* in_sizes, int n_in,
                              void* d_out, int out_size, void* d_ws, size_t ws_size,
                              hipStream_t stream) {
    const float* x     = (const float*)d_in[0];
    const float* nw    = (const float*)d_in[1];
    const float* nb    = (const float*)d_in[2];
    const float* qkvw  = (const float*)d_in[3];
    const float* projw = (const float*)d_in[4];
    const float* asc   = (const float*)d_in[5];
    const float* rpb   = (const float*)d_in[6];

    const int H = 256, W = 256;
    const int B = in_sizes[0] / (CH * H * W);
    const int nwin = B * (H / WSZ) * (W / WSZ);
    const int nblk = nwin / WPB;     // nwin = B*1024, always divisible by 4

    // workspace: [0,24576) qkv bf16; [24576,32768) proj bf16; [32768,98304) bias fp32
    u16*   wq = (u16*)d_ws;
    u16*   wp = (u16*)((char*)d_ws + 24576);
    float* bl = (float*)((char*)d_ws + 32768);

    prep<<<64, 256, 0, stream>>>(qkvw, projw, rpb, wq, wp, bl);
    win_attn<<<nblk, 256, 0, stream>>>(x, nw, nb, wq, wp, asc, bl,
                                       (float*)d_out, B, H, W);
}

// Round 8
// 475.177 us; speedup vs baseline: 2.7942x; 2.7942x over previous
//
#include <hip/hip_runtime.h>
#include <hip/hip_bf16.h>

#define WSZ 8
#define NHE 4
#define CH 64

typedef unsigned short u16;
typedef unsigned int u32;
typedef __attribute__((ext_vector_type(8))) short short8;
typedef __attribute__((ext_vector_type(4))) short short4v;
typedef __attribute__((ext_vector_type(4))) float float4v;

// Native bf16 conversion (RNE). Compiler packs pairs into v_cvt_pk_bf16_f32.
__device__ __forceinline__ u16 f2bf(float f) {
    __hip_bfloat16 h = __float2bfloat16(f);
    return __builtin_bit_cast(u16, h);
}
// XOR swizzle for [row][64] bf16 arrays: keeps 8-elem (16B) chunks intact,
// spreads the 8 chunk slots across banks by row.
__device__ __forceinline__ int SW(int row, int col) {
    return row * 64 + (col ^ ((row & 7) << 3));
}

#define MFMA(a, b, c) __builtin_amdgcn_mfma_f32_16x16x32_bf16(a, b, c, 0, 0, 0)
#define QKSC 0.36067376022224085f   /* 0.25 * log2(e) */

// ---- pre-kernel: bf16 weights in per-lane fragment layout + rpb expanded to
// a coalesced bias table matching the TRANSPOSED-S lane mapping (verified R3/R5/R6),
// PRE-SCALED by log2(e) for the exp2-domain softmax:
//   idx = ((h*4+mt)*64 + lane)*16 + nt*4 + r,
//   query tokm = mt*16 + (lane&15), key tokn = nt*16 + (lane>>4)*4 + r
__global__ void prep(const float* __restrict__ qkvw, const float* __restrict__ projw,
                     const float* __restrict__ rpb,
                     u16* __restrict__ wq, u16* __restrict__ wp, float* __restrict__ bl)
{
    int t = blockIdx.x * 256 + threadIdx.x;   // 64 blocks x 256 = 16384
    if (t < 12288) {  // qkv weights: layout [nt][kt][q][nl][8]
        int j = t & 7, nl = (t >> 3) & 15, q = (t >> 7) & 3, kt = (t >> 9) & 1, nt = t >> 10;
        wq[t] = f2bf(qkvw[(nt * 16 + nl) * CH + kt * 32 + q * 8 + j]);
    }
    if (t < 4096) {   // proj weights: layout [wv][kt][q][nl][8]
        int j = t & 7, nl = (t >> 3) & 15, q = (t >> 7) & 3, kt = (t >> 9) & 1, wv = t >> 10;
        wp[t] = f2bf(projw[(wv * 16 + nl) * CH + kt * 32 + q * 8 + j]);
    }
    if (t < 16384) {  // bias table for transposed-S softmax (log2-domain)
        int r = t & 3, nt = (t >> 2) & 3, lane = (t >> 4) & 63, mt = (t >> 10) & 3, h = t >> 12;
        int nl = lane & 15, q = lane >> 4;
        int tokm = mt * 16 + nl, tokn = nt * 16 + q * 4 + r;
        int im = tokm >> 3, jm = tokm & 7, in_ = tokn >> 3, jn = tokn & 7;
        bl[t] = rpb[((im - in_ + 7) * 15 + (jm - jn + 7)) * NHE + h] * 1.44269504088896341f;
    }
}

// PAIR-BLOCK: 512 threads / 8 waves; waves 0-3 = window 2k, waves 4-7 = window
// 2k+1 (horizontally adjacent). Each 64B x/out line is half in each window ->
// both halves are read/written by the SAME block in the SAME phase: full-line
// HBM transactions guaranteed (R6's FETCH/WRITE inflation was timing-dependent
// half-line splits across blocks).
// Per-window LDS slice = 24576 B (x in registers), total 48 KB -> 3 blocks/CU
// (24 waves/CU). Slice map (verified R6, all aliases barrier-separated or
// same-wave in-order):
//   [0,8192)     XN bf16 swz (ph1-2a) -> QO bf16 (ph2b+, after bar3)
//   [8192,16384) KS bf16 (ph2b+)
//   [16384,24576) PS/PS2 LN partials (ph0-1) -> VS bf16 [64ch][64tok] (ph2b+);
//                 ph3: wave h reuses its own VS rows h*16..+15 as P after vfr load.
__global__ __launch_bounds__(512, 6) void win_attn(
    const float* __restrict__ x, const float* __restrict__ nw, const float* __restrict__ nb,
    const u16* __restrict__ wq, const u16* __restrict__ wp,
    const float* __restrict__ ascale, const float* __restrict__ biasl,
    float* __restrict__ out, int B, int H, int W)
{
    const int HWsz = H * W;
    const int nww = W / WSZ, nwh = H / WSZ, npr = nww >> 1;
    // XCD-chunked swizzle over pair-blocks (nblk = B*512, %8==0).
    const int NBLK = (int)gridDim.x;
    const int pw = (blockIdx.x & 7) * (NBLK >> 3) + ((int)blockIdx.x >> 3);
    const int wwp = pw % npr;
    const int t1  = pw / npr;
    const int wh  = t1 % nwh;
    const int b   = t1 / nwh;

    const int tid  = threadIdx.x;
    const int lane = tid & 63;
    const int wv   = tid >> 6;    // 0..7
    const int ws   = wv >> 2;     // which window of the pair
    const int wvl  = wv & 3;      // wave within window
    const int q    = lane >> 4;   // quad
    const int nl   = lane & 15;

    __shared__ alignas(16) char smem[49152];
    char* sm = smem + ws * 24576;
    u16*   XN  = (u16*)(sm);              // ph2b+: QO
    u16*   QO  = (u16*)(sm);
    u16*   KS  = (u16*)(sm + 8192);
    u16*   VS  = (u16*)(sm + 16384);
    float* PS  = (float*)(sm + 16384);
    float* PS2 = PS + 256;

    const int ww = wwp * 2 + ws;
    const int rowbase = (wh * WSZ) * W + ww * WSZ;
    const float* xw = x + (size_t)b * CH * HWsz + rowbase;
    const int tokoff = (lane >> 3) * W + (lane & 7);

    // ---- phase 0: x -> registers (lane = token, channels wvl*16..+15); LN partials ----
    float xv[16];
    {
        const float* xc = xw + (size_t)(wvl * 16) * HWsz + tokoff;
        #pragma unroll
        for (int ci = 0; ci < 16; ci++) xv[ci] = xc[(size_t)ci * HWsz];
        float s = 0.f, s2 = 0.f;
        #pragma unroll
        for (int ci = 0; ci < 16; ci++) { s += xv[ci]; s2 += xv[ci] * xv[ci]; }
        PS[wvl * 64 + lane] = s;
        PS2[wvl * 64 + lane] = s2;
    }
    __syncthreads();   // bar1: PS ready

    // ---- phase 1: per-lane LN finalize for token=lane; vector-write XN ----
    {
        float s  = PS[lane]  + PS[64 + lane]  + PS[128 + lane]  + PS[192 + lane];
        float s2 = PS2[lane] + PS2[64 + lane] + PS2[128 + lane] + PS2[192 + lane];
        float mu  = s * (1.f / 64.f);
        float var = s2 * (1.f / 64.f) - mu * mu;
        float rs  = rsqrtf(var + 1e-5f);
        float v[16];
        #pragma unroll
        for (int ci = 0; ci < 16; ci++) {
            int c = wvl * 16 + ci;                      // wave-uniform -> s_load nw/nb
            v[ci] = (xv[ci] - mu) * rs * nw[c] + nb[c];
        }
        #pragma unroll
        for (int g = 0; g < 2; g++) {
            short8 pk;
            #pragma unroll
            for (int j = 0; j < 8; j++) pk[j] = (short)f2bf(v[g * 8 + j]);
            *(short8*)&XN[lane * 64 + ((wvl * 16 + g * 8) ^ ((lane & 7) << 3))] = pk;
        }
    }
    __syncthreads();   // bar2: XN ready

    // ---- phase 2a: A-fragments + weights; prefetch residual x into regs ----
    short8 afr[4][2];
    #pragma unroll
    for (int mt = 0; mt < 4; mt++)
        #pragma unroll
        for (int kt = 0; kt < 2; kt++) {
            int m = mt * 16 + nl;
            int phys = (kt * 4 + q) ^ (m & 7);
            afr[mt][kt] = *(short8*)&XN[m * 64 + phys * 8];
        }
    short8 bfrs[3][2];
    #pragma unroll
    for (int nt3 = 0; nt3 < 3; nt3++) {
        int nt = wvl * 3 + nt3;
        #pragma unroll
        for (int kt = 0; kt < 2; kt++)
            bfrs[nt3][kt] = *(const short8*)&wq[((((nt * 2 + kt) * 4 + q) * 16) + nl) * 8];
    }
    const int ch = wvl * 16 + nl;
    float4v xr[4];
    {
        const float* xrp = xw + (size_t)ch * HWsz;   // residual (L2-hot); hidden under ph2b/ph3
        #pragma unroll
        for (int mt = 0; mt < 4; mt++) {
            int tok0 = mt * 16 + q * 4;
            xr[mt] = *(const float4v*)(xrp + (tok0 >> 3) * W + (tok0 & 7));
        }
    }
    __syncthreads();   // bar3: XN consumed -> QO may overwrite it

    // ---- phase 2b: QKV GEMM (M=64 tok, N=192, K=64), wave wvl owns n-tiles 3w..3w+2 ----
    #pragma unroll
    for (int nt3 = 0; nt3 < 3; nt3++) {
        int nt = wvl * 3 + nt3;
        int which = nt >> 2;                 // 0:Q 1:K 2:V (wave-uniform)
        int chb = (nt & 3) * 16 + nl;        // output channel within q/k/v
        #pragma unroll
        for (int mt = 0; mt < 4; mt++) {
            float4v acc = {0.f, 0.f, 0.f, 0.f};
            acc = MFMA(afr[mt][0], bfrs[nt3][0], acc);
            acc = MFMA(afr[mt][1], bfrs[nt3][1], acc);
            int tok0 = mt * 16 + q * 4;
            if (which == 0) {
                #pragma unroll
                for (int r = 0; r < 4; r++) QO[SW(tok0 + r, chb)] = f2bf(acc[r]);
            } else if (which == 1) {
                #pragma unroll
                for (int r = 0; r < 4; r++) KS[SW(tok0 + r, chb)] = f2bf(acc[r]);
            } else {
                short4v pk;
                pk[0] = (short)f2bf(acc[0]); pk[1] = (short)f2bf(acc[1]);
                pk[2] = (short)f2bf(acc[2]); pk[3] = (short)f2bf(acc[3]);
                int pt = tok0 ^ ((chb & 7) << 3);    // V is [ch][tok]: 4 toks contiguous
                *(short4v*)&VS[chb * 64 + pt] = pk;
            }
        }
    }
    __syncthreads();   // bar4: Q/K/V ready

    // ---- phase 3: attention, wave = head wvl; K=16 zero-padded to MFMA K=32 ----
    // S^T trick (verified R3/R5/R6): MFMA(kfr, qf) -> lane (nl,q) reg r holds
    // S[query = mt*16+nl][key = nt*16+q*4+r]; softmax = 15 local ops + 2 shuffles.
    {
        const int h = wvl;
        const short8 zero8 = {0, 0, 0, 0, 0, 0, 0, 0};
        short8 kfr[4], vfr[2];
        #pragma unroll
        for (int nt = 0; nt < 4; nt++) {
            if (q < 2) {
                int n = nt * 16 + nl;
                int phys = (h * 2 + q) ^ (n & 7);
                kfr[nt] = *(short8*)&KS[n * 64 + phys * 8];
            } else kfr[nt] = zero8;
        }
        #pragma unroll
        for (int kt = 0; kt < 2; kt++) {
            int c = h * 16 + nl;
            int phys = (kt * 4 + q) ^ (c & 7);
            vfr[kt] = *(short8*)&VS[c * 64 + phys * 8];
        }
        // vfr in regs -> wave h's own VS slice (rows h*16..+15, 2KB) becomes P.
        u16* Pw = VS + h * 1024;
        #pragma unroll
        for (int mt = 0; mt < 4; mt++) {
            short8 qf;
            if (q < 2) {
                int m = mt * 16 + nl;
                int phys = (h * 2 + q) ^ (m & 7);
                qf = *(short8*)&QO[m * 64 + phys * 8];
            } else qf = zero8;
            const float4v* bp = (const float4v*)(biasl + ((((h * 4 + mt) * 64) + lane) << 4));
            float4v sacc[4];
            #pragma unroll
            for (int nt = 0; nt < 4; nt++) {
                float4v z = {0.f, 0.f, 0.f, 0.f};
                sacc[nt] = MFMA(kfr[nt], qf, z);   // transposed S
            }
            float p[16], mx = -1e30f;
            #pragma unroll
            for (int nt = 0; nt < 4; nt++) {
                float4v blv = bp[nt];
                #pragma unroll
                for (int r = 0; r < 4; r++) {
                    float s = fmaf(sacc[nt][r], QKSC, blv[r]);   // log2-domain score
                    p[nt * 4 + r] = s;
                    mx = fmaxf(mx, s);
                }
            }
            mx = fmaxf(mx, __shfl_xor(mx, 16, 64));
            mx = fmaxf(mx, __shfl_xor(mx, 32, 64));
            float sum = 0.f;
            #pragma unroll
            for (int i = 0; i < 16; i++) {
                float e = __builtin_amdgcn_exp2f(p[i] - mx);
                p[i] = e;
                sum += e;
            }
            sum += __shfl_xor(sum, 16, 64);
            sum += __shfl_xor(sum, 32, 64);
            float inv = __builtin_amdgcn_rcpf(sum);
            #pragma unroll
            for (int nt = 0; nt < 4; nt++)
                #pragma unroll
                for (int r = 0; r < 4; r++)
                    Pw[SW(nl, nt * 16 + q * 4 + r)] = f2bf(p[nt * 4 + r] * inv);
            // PV: O[mt] = P[16x64] @ V[64x16]  (wave-local LDS, in-order DS ops)
            float4v oacc = {0.f, 0.f, 0.f, 0.f};
            #pragma unroll
            for (int kt = 0; kt < 2; kt++) {
                int phys = (kt * 4 + q) ^ (nl & 7);
                short8 pf = *(short8*)&Pw[nl * 64 + phys * 8];
                oacc = MFMA(pf, vfr[kt], oacc);
            }
            #pragma unroll
            for (int r = 0; r < 4; r++)
                QO[SW(mt * 16 + q * 4 + r, h * 16 + nl)] = f2bf(oacc[r]);
        }
    }
    __syncthreads();   // bar5: O ready

    // ---- phase 4: proj + residual; wave wvl owns out-channel tile wvl ----
    {
        const float asc = ascale[0];
        short8 wfr[2];
        #pragma unroll
        for (int kt = 0; kt < 2; kt++)
            wfr[kt] = *(const short8*)&wp[((((wvl * 2 + kt) * 4 + q) * 16) + nl) * 8];
        float* outp = out + ((size_t)b * CH + ch) * HWsz + rowbase;
        #pragma unroll
        for (int mt = 0; mt < 4; mt++) {
            float4v yacc = {0.f, 0.f, 0.f, 0.f};
            #pragma unroll
            for (int kt = 0; kt < 2; kt++) {
                int m = mt * 16 + nl;
                int phys = (kt * 4 + q) ^ (m & 7);
                short8 of = *(short8*)&QO[m * 64 + phys * 8];
                yacc = MFMA(of, wfr[kt], yacc);
            }
            int tok0 = mt * 16 + q * 4;                  // 4 consecutive tokens = 4 consecutive j
            int i = tok0 >> 3, j = tok0 & 7;
            float4v y;
            y[0] = xr[mt][0] + asc * yacc[0];
            y[1] = xr[mt][1] + asc * yacc[1];
            y[2] = xr[mt][2] + asc * yacc[2];
            y[3] = xr[mt][3] + asc * yacc[3];
            *(float4v*)(outp + i * W + j) = y;
        }
    }
}

extern "C" void kernel_launch(void* const* d_in, const int* in_sizes, int n_in,
                              void* d_out, int out_size, void* d_ws, size_t ws_size,
                              hipStream_t stream) {
    const float* x     = (const float*)d_in[0];
    const float* nw    = (const float*)d_in[1];
    const float* nb    = (const float*)d_in[2];
    const float* qkvw  = (const float*)d_in[3];
    const float* projw = (const float*)d_in[4];
    const float* asc   = (const float*)d_in[5];
    const float* rpb   = (const float*)d_in[6];

    const int H = 256, W = 256;
    const int B = in_sizes[0] / (CH * H * W);
    const int nwin = B * (H / WSZ) * (W / WSZ);
    const int nblk = nwin / 2;       // pair-blocks; B*512, %8 == 0

    // workspace: [0,24576) qkv bf16; [24576,32768) proj bf16; [32768,98304) bias fp32
    u16*   wq = (u16*)d_ws;
    u16*   wp = (u16*)((char*)d_ws + 24576);
    float* bl = (float*)((char*)d_ws + 32768);

    prep<<<64, 256, 0, stream>>>(qkvw, projw, rpb, wq, wp, bl);
    win_attn<<<nblk, 512, 0, stream>>>(x, nw, nb, wq, wp, asc, bl,
                                       (float*)d_out, B, H, W);
}

// Round 9
// 330.247 us; speedup vs baseline: 4.0204x; 1.4389x over previous
//
#include <hip/hip_runtime.h>
#include <hip/hip_bf16.h>

#define WSZ 8
#define NHE 4
#define CH 64

typedef unsigned short u16;
typedef __attribute__((ext_vector_type(8))) short short8;
typedef __attribute__((ext_vector_type(4))) short short4v;
typedef __attribute__((ext_vector_type(4))) float float4v;

// Native bf16 conversion (RNE). Compiler packs pairs into v_cvt_pk_bf16_f32.
__device__ __forceinline__ u16 f2bf(float f) {
    __hip_bfloat16 h = __float2bfloat16(f);
    return __builtin_bit_cast(u16, h);
}
// XOR swizzle for [row][64] bf16 arrays: keeps 8-elem (16B) chunks intact,
// spreads the 8 chunk slots across banks by row.
__device__ __forceinline__ int SW(int row, int col) {
    return row * 64 + (col ^ ((row & 7) << 3));
}

#define MFMA(a, b, c) __builtin_amdgcn_mfma_f32_16x16x32_bf16(a, b, c, 0, 0, 0)
#define QKSC 0.36067376022224085f   /* 0.25 * log2(e) */

// ---- pre-kernel (verified R3/R5): bf16 weights in per-lane fragment layout +
// rpb expanded to a coalesced bias table for the TRANSPOSED-S lane mapping,
// PRE-SCALED by log2(e):
//   idx = ((h*4+mt)*64 + lane)*16 + nt*4 + r,
//   query tokm = mt*16 + (lane&15), key tokn = nt*16 + (lane>>4)*4 + r
__global__ void prep(const float* __restrict__ qkvw, const float* __restrict__ projw,
                     const float* __restrict__ rpb,
                     u16* __restrict__ wq, u16* __restrict__ wp, float* __restrict__ bl)
{
    int t = blockIdx.x * 256 + threadIdx.x;   // 64 blocks x 256 = 16384
    if (t < 12288) {  // qkv weights: layout [nt][kt][q][nl][8]
        int j = t & 7, nl = (t >> 3) & 15, q = (t >> 7) & 3, kt = (t >> 9) & 1, nt = t >> 10;
        wq[t] = f2bf(qkvw[(nt * 16 + nl) * CH + kt * 32 + q * 8 + j]);
    }
    if (t < 4096) {   // proj weights: layout [wv][kt][q][nl][8]
        int j = t & 7, nl = (t >> 3) & 15, q = (t >> 7) & 3, kt = (t >> 9) & 1, wv = t >> 10;
        wp[t] = f2bf(projw[(wv * 16 + nl) * CH + kt * 32 + q * 8 + j]);
    }
    if (t < 16384) {  // bias table for transposed-S softmax (log2-domain)
        int r = t & 3, nt = (t >> 2) & 3, lane = (t >> 4) & 63, mt = (t >> 10) & 3, h = t >> 12;
        int nl = lane & 15, q = lane >> 4;
        int tokm = mt * 16 + nl, tokn = nt * 16 + q * 4 + r;
        int im = tokm >> 3, jm = tokm & 7, in_ = tokn >> 3, jn = tokn & 7;
        bl[t] = rpb[((im - in_ + 7) * 15 + (jm - jn + 7)) * NHE + h] * 1.44269504088896341f;
    }
}

// One block per window, 256 threads / 4 waves, LDS = 32768 B -> 5 blocks/CU
// (the R5 config with verified-good memory locality).
// WAVE-LOCAL HEAD PIPELINE: wave w computes QKV n-tiles {w, w+4, w+8} = exactly
// head w's Q/K/V slices, staged in wave w's private 6KB LDS slice. The
// ph2b -> ph3 boundary is then same-wave (DS ops in-order) -> NO barrier:
// the 48-MFMA + softmax bulk runs barrier-free and waves desynchronize.
// LDS map (all aliases barrier-separated or same-wave in-order):
//   [0,8192)      XN bf16 [64tok][64ch] swz (ph1-2a) -> O tile (ph3+, after bar3)
//   [8192,32768)  per-wave 6144B slices: QW[64][16], KW[64][16], VW[16][64]swz;
//                 KW reused as P[16][64]swz in ph3 (kfr already in regs).
//   [8192,10496)  PS/PS2 LN partials (ph0-1 only; staging written after bar3).
__global__ __launch_bounds__(256, 5) void win_attn(
    const float* __restrict__ x, const float* __restrict__ nw, const float* __restrict__ nb,
    const u16* __restrict__ wq, const u16* __restrict__ wp,
    const float* __restrict__ ascale, const float* __restrict__ biasl,
    float* __restrict__ out, int B, int H, int W)
{
    const int HWsz = H * W;
    const int nww = W / WSZ, nwh = H / WSZ;
    // XCD-chunked swizzle: nwin = B*1024, %8==0.
    const int win = (blockIdx.x & 7) * ((int)gridDim.x >> 3) + (blockIdx.x >> 3);
    const int ww = win % nww;
    const int t1 = win / nww;
    const int wh = t1 % nwh;
    const int b  = t1 / nwh;

    const int tid  = threadIdx.x;
    const int lane = tid & 63;
    const int wv   = tid >> 6;
    const int q    = lane >> 4;   // quad
    const int nl   = lane & 15;

    __shared__ alignas(16) char smem[32768];
    u16*   XN  = (u16*)(smem);              // ph3+: O tile
    u16*   QW  = (u16*)(smem + 8192) + wv * 3072;   // [64tok][16ch] linear
    u16*   KW  = QW + 1024;                 // [64tok][16ch] linear; ph3: P
    u16*   VW  = QW + 2048;                 // [16ch][64tok] tok-swizzled
    float* PS  = (float*)(smem + 8192);
    float* PS2 = PS + 256;

    const int rowbase = (wh * WSZ) * W + ww * WSZ;
    const float* xw = x + (size_t)b * CH * HWsz + rowbase;
    const int tokoff = (lane >> 3) * W + (lane & 7);

    // ---- phase 0: x -> registers (lane = token, channels wv*16..+15); LN partials ----
    float xv[16];
    {
        const float* xc = xw + (size_t)(wv * 16) * HWsz + tokoff;
        #pragma unroll
        for (int ci = 0; ci < 16; ci++) xv[ci] = xc[(size_t)ci * HWsz];
        float s = 0.f, s2 = 0.f;
        #pragma unroll
        for (int ci = 0; ci < 16; ci++) { s += xv[ci]; s2 += xv[ci] * xv[ci]; }
        PS[wv * 64 + lane] = s;
        PS2[wv * 64 + lane] = s2;
    }
    __syncthreads();   // bar1: PS ready

    // ---- phase 1: per-lane LN finalize for token=lane; vector-write XN ----
    {
        float s  = PS[lane]  + PS[64 + lane]  + PS[128 + lane]  + PS[192 + lane];
        float s2 = PS2[lane] + PS2[64 + lane] + PS2[128 + lane] + PS2[192 + lane];
        float mu  = s * (1.f / 64.f);
        float var = s2 * (1.f / 64.f) - mu * mu;
        float rs  = rsqrtf(var + 1e-5f);
        float v[16];
        #pragma unroll
        for (int ci = 0; ci < 16; ci++) {
            int c = wv * 16 + ci;                       // wave-uniform -> s_load nw/nb
            v[ci] = (xv[ci] - mu) * rs * nw[c] + nb[c];
        }
        #pragma unroll
        for (int g = 0; g < 2; g++) {
            short8 pk;
            #pragma unroll
            for (int j = 0; j < 8; j++) pk[j] = (short)f2bf(v[g * 8 + j]);
            *(short8*)&XN[lane * 64 + ((wv * 16 + g * 8) ^ ((lane & 7) << 3))] = pk;
        }
    }
    __syncthreads();   // bar2: XN ready

    // ---- phase 2a: A-fragments (ALL XN reads) + head-w weight fragments ----
    short8 afr[4][2];
    #pragma unroll
    for (int mt = 0; mt < 4; mt++)
        #pragma unroll
        for (int kt = 0; kt < 2; kt++) {
            int m = mt * 16 + nl;
            int phys = (kt * 4 + q) ^ (m & 7);
            afr[mt][kt] = *(short8*)&XN[m * 64 + phys * 8];
        }
    short8 bfrs[3][2];
    #pragma unroll
    for (int nt3 = 0; nt3 < 3; nt3++) {
        int nt = wv + nt3 * 4;               // head-w slices of Q/K/V
        #pragma unroll
        for (int kt = 0; kt < 2; kt++)
            bfrs[nt3][kt] = *(const short8*)&wq[((((nt * 2 + kt) * 4 + q) * 16) + nl) * 8];
    }
    __syncthreads();   // bar3: XN consumed -> O may overwrite it; PS dead -> staging ok

    // ---- phase 2b: QKV GEMM into PRIVATE per-wave staging (no barrier after) ----
    #pragma unroll
    for (int nt3 = 0; nt3 < 3; nt3++) {      // nt3: 0=Q, 1=K, 2=V (head-local ch = nl)
        #pragma unroll
        for (int mt = 0; mt < 4; mt++) {
            float4v acc = {0.f, 0.f, 0.f, 0.f};
            acc = MFMA(afr[mt][0], bfrs[nt3][0], acc);
            acc = MFMA(afr[mt][1], bfrs[nt3][1], acc);
            int tok0 = mt * 16 + q * 4;
            if (nt3 == 0) {
                #pragma unroll
                for (int r = 0; r < 4; r++) QW[(tok0 + r) * 16 + nl] = f2bf(acc[r]);
            } else if (nt3 == 1) {
                #pragma unroll
                for (int r = 0; r < 4; r++) KW[(tok0 + r) * 16 + nl] = f2bf(acc[r]);
            } else {
                short4v pk;
                pk[0] = (short)f2bf(acc[0]); pk[1] = (short)f2bf(acc[1]);
                pk[2] = (short)f2bf(acc[2]); pk[3] = (short)f2bf(acc[3]);
                int pt = tok0 ^ ((nl & 7) << 3);    // VW [ch][tok]: 4 toks contiguous
                *(short4v*)&VW[nl * 64 + pt] = pk;
            }
        }
    }
    // NO barrier: ph3 reads only this wave's own staging (same-wave DS in-order).

    // ---- phase 3: attention for head h=wv; K=16 zero-padded to MFMA K=32 ----
    // S^T trick (verified R3/R5/R6): MFMA(kfr, qf) -> lane (nl,q) reg r holds
    // S[query = mt*16+nl][key = nt*16+q*4+r]; softmax = 15 local ops + 2 shuffles.
    {
        const int h = wv;
        const short8 zero8 = {0, 0, 0, 0, 0, 0, 0, 0};
        short8 kfr[4], vfr[2];
        #pragma unroll
        for (int nt = 0; nt < 4; nt++)
            kfr[nt] = (q < 2) ? *(short8*)&KW[(nt * 16 + nl) * 16 + q * 8] : zero8;
        #pragma unroll
        for (int kt = 0; kt < 2; kt++) {
            int phys = (kt * 4 + q) ^ (nl & 7);
            vfr[kt] = *(short8*)&VW[nl * 64 + phys * 8];
        }
        u16* Pw = KW;   // kfr in regs -> KW (2KB) becomes P [16q][64k] swz
        #pragma unroll
        for (int mt = 0; mt < 4; mt++) {
            short8 qf = (q < 2) ? *(short8*)&QW[(mt * 16 + nl) * 16 + q * 8] : zero8;
            const float4v* bp = (const float4v*)(biasl + ((((h * 4 + mt) * 64) + lane) << 4));
            float4v sacc[4];
            #pragma unroll
            for (int nt = 0; nt < 4; nt++) {
                float4v z = {0.f, 0.f, 0.f, 0.f};
                sacc[nt] = MFMA(kfr[nt], qf, z);   // transposed S
            }
            float p[16], mx = -1e30f;
            #pragma unroll
            for (int nt = 0; nt < 4; nt++) {
                float4v blv = bp[nt];
                #pragma unroll
                for (int r = 0; r < 4; r++) {
                    float s = fmaf(sacc[nt][r], QKSC, blv[r]);   // log2-domain score
                    p[nt * 4 + r] = s;
                    mx = fmaxf(mx, s);
                }
            }
            mx = fmaxf(mx, __shfl_xor(mx, 16, 64));
            mx = fmaxf(mx, __shfl_xor(mx, 32, 64));
            float sum = 0.f;
            #pragma unroll
            for (int i = 0; i < 16; i++) {
                float e = __builtin_amdgcn_exp2f(p[i] - mx);
                p[i] = e;
                sum += e;
            }
            sum += __shfl_xor(sum, 16, 64);
            sum += __shfl_xor(sum, 32, 64);
            float inv = __builtin_amdgcn_rcpf(sum);
            #pragma unroll
            for (int nt = 0; nt < 4; nt++)
                #pragma unroll
                for (int r = 0; r < 4; r++)
                    Pw[SW(nl, nt * 16 + q * 4 + r)] = f2bf(p[nt * 4 + r] * inv);
            // PV: O[mt] = P[16x64] @ V[64x16]  (wave-local LDS, in-order DS ops)
            float4v oacc = {0.f, 0.f, 0.f, 0.f};
            #pragma unroll
            for (int kt = 0; kt < 2; kt++) {
                int phys = (kt * 4 + q) ^ (nl & 7);
                short8 pf = *(short8*)&Pw[nl * 64 + phys * 8];
                oacc = MFMA(pf, vfr[kt], oacc);
            }
            #pragma unroll
            for (int r = 0; r < 4; r++)
                XN[SW(mt * 16 + q * 4 + r, h * 16 + nl)] = f2bf(oacc[r]);
        }
    }
    __syncthreads();   // bar4: O (in XN) ready

    // ---- phase 4: proj + residual; wave w owns out-channel tile w ----
    {
        const float asc = ascale[0];
        const int ch = wv * 16 + nl;
        const float* xrp = xw + (size_t)ch * HWsz;   // residual re-read (L2-hot)
        float4v xr[4];
        #pragma unroll
        for (int mt = 0; mt < 4; mt++) {
            int tok0 = mt * 16 + q * 4;
            xr[mt] = *(const float4v*)(xrp + (tok0 >> 3) * W + (tok0 & 7));
        }
        short8 wfr[2];
        #pragma unroll
        for (int kt = 0; kt < 2; kt++)
            wfr[kt] = *(const short8*)&wp[((((wv * 2 + kt) * 4 + q) * 16) + nl) * 8];
        float* outp = out + ((size_t)b * CH + ch) * HWsz + rowbase;
        #pragma unroll
        for (int mt = 0; mt < 4; mt++) {
            float4v yacc = {0.f, 0.f, 0.f, 0.f};
            #pragma unroll
            for (int kt = 0; kt < 2; kt++) {
                int m = mt * 16 + nl;
                int phys = (kt * 4 + q) ^ (m & 7);
                short8 of = *(short8*)&XN[m * 64 + phys * 8];
                yacc = MFMA(of, wfr[kt], yacc);
            }
            int tok0 = mt * 16 + q * 4;                  // 4 consecutive tokens = 4 consecutive j
            int i = tok0 >> 3, j = tok0 & 7;
            float4v y;
            y[0] = xr[mt][0] + asc * yacc[0];
            y[1] = xr[mt][1] + asc * yacc[1];
            y[2] = xr[mt][2] + asc * yacc[2];
            y[3] = xr[mt][3] + asc * yacc[3];
            *(float4v*)(outp + i * W + j) = y;
        }
    }
}

extern "C" void kernel_launch(void* const* d_in, const int* in_sizes, int n_in,
                              void* d_out, int out_size, void* d_ws, size_t ws_size,
                              hipStream_t stream) {
    const float* x     = (const float*)d_in[0];
    const float* nw    = (const float*)d_in[1];
    const float* nb    = (const float*)d_in[2];
    const float* qkvw  = (const float*)d_in[3];
    const float* projw = (const float*)d_in[4];
    const float* asc   = (const float*)d_in[5];
    const float* rpb   = (const float*)d_in[6];

    const int H = 256, W = 256;
    const int B = in_sizes[0] / (CH * H * W);
    const int nwin = B * (H / WSZ) * (W / WSZ);

    // workspace: [0,24576) qkv bf16; [24576,32768) proj bf16; [32768,98304) bias fp32
    u16*   wq = (u16*)d_ws;
    u16*   wp = (u16*)((char*)d_ws + 24576);
    float* bl = (float*)((char*)d_ws + 32768);

    prep<<<64, 256, 0, stream>>>(qkvw, projw, rpb, wq, wp, bl);
    win_attn<<<nwin, 256, 0, stream>>>(x, nw, nb, wq, wp, asc, bl,
                                       (float*)d_out, B, H, W);
}